// Round 5
// baseline (360.444 us; speedup 1.0000x reference)
//
#include <hip/hip_runtime.h>
#include <hip/hip_fp16.h>

// ---------------------------------------------------------------------------
// IN=128, H=8, R=16, D=16 -> H*R = H*D = 128
// K = h @ q, Q = h @ p, V = h @ Wv   (K uses weight "q", Q uses weight "p")
// score = exp(clip((K[src]*Q[dst]).sum(r)/4, -5, 5))
// out = seg_sum(score*V[src], dst) / max(seg_sum(score,dst), eps-fixup)
//
// R13: head-per-XCD aggregation (head = blockIdx&7): per-head KV slice is
//      3.2MB -> fits one XCD's 4MiB L2. FETCH 350MB -> 55MB (verified).
// R15: quad-per-edge (1 line-touch/edge-head, DPP quad ops): 150 -> 90us.
// R16: 4-deep pipeline: NO change (89us) -> aggregate is not simply
//      L2-latency bound; ~89us is a mixed scattered-64B-service/TLP floor.
//      Leave aggregate alone.
// R17: the OTHER ~142us is the CSR build (LDS bucket sort + ebuf round-trip
//      + fine re-sort). Replace with direct counting-sort placement:
//      D1 count branch: atomicAdd(deg[dst]) (no LDS, hides under GEMM)
//      D2 bucket_offsets: per-bucket scan -> offs/cursor/nodeord
//      D3 place: pos = atomicAdd(cursor[dst]); csr[pos] = src
//      fine_scatter + ebuf deleted. Aggregate inputs identical semantics.
// ---------------------------------------------------------------------------

#define HNODE 64        // nodes per GEMM block
#define EPB   4096      // edges per count/place block
#define BKT_SHIFT 7     // 128 nodes per bucket
#define BKT_CAP 5120    // bucket mean 4092 + 16 sigma

typedef _Float16 f16x8 __attribute__((ext_vector_type(8)));
typedef float    f32x4 __attribute__((ext_vector_type(4)));
typedef _Float16 hv2   __attribute__((ext_vector_type(2)));

__device__ __forceinline__ float fdot2(unsigned a, unsigned b, float c) {
#if __has_builtin(__builtin_amdgcn_fdot2)
    return __builtin_amdgcn_fdot2(__builtin_bit_cast(hv2, a),
                                  __builtin_bit_cast(hv2, b), c, false);
#else
    __half2 ah = *(__half2*)&a, bh = *(__half2*)&b;
    float2 af = __half22float2(ah), bf = __half22float2(bh);
    return c + af.x * bf.x + af.y * bf.y;
#endif
}

__device__ __forceinline__ float2 h2f(unsigned u) {
    __half2 hh = *(__half2*)&u;
    return __half22float2(hh);
}

__device__ __forceinline__ unsigned pack2(float a, float b) {
    __half2 hh = __floats2half2_rn(a, b);
    return *(unsigned*)&hh;
}

__device__ __forceinline__ float clamp5(float x) {
#if __has_builtin(__builtin_amdgcn_fmed3f)
    return __builtin_amdgcn_fmed3f(x, -5.f, 5.f);   // v_med3_f32 = clamp idiom
#else
    return fminf(fmaxf(x, -5.f), 5.f);
#endif
}

// ---- quad-scope cross-lane via DPP (VALU pipe, no LDS traffic) -------------
#if __has_builtin(__builtin_amdgcn_mov_dpp)
#define QBCAST(v, J) __builtin_amdgcn_mov_dpp((v), (J) * 0x55, 0xF, 0xF, true)
__device__ __forceinline__ float qadd_xor1(float x) {
    int y = __builtin_amdgcn_mov_dpp(__float_as_int(x), 0xB1, 0xF, 0xF, true);
    return x + __int_as_float(y);
}
__device__ __forceinline__ float qadd_xor2(float x) {
    int y = __builtin_amdgcn_mov_dpp(__float_as_int(x), 0x4E, 0xF, 0xF, true);
    return x + __int_as_float(y);
}
#else
#define QBCAST(v, J) __shfl((v), ((threadIdx.x & 63) & ~3) + (J), 64)
__device__ __forceinline__ float qadd_xor1(float x) { return x + __shfl_xor(x, 1); }
__device__ __forceinline__ float qadd_xor2(float x) { return x + __shfl_xor(x, 2); }
#endif

// ---------------- D0: weight transpose+convert + zero degree array ----------
__global__ __launch_bounds__(256) void wt_convert_kernel(
    const float* __restrict__ Wq, const float* __restrict__ Wp,
    const float* __restrict__ Wv, __half* __restrict__ Wt,
    int* __restrict__ deg, int N)
{
    int o = blockIdx.x * 256 + threadIdx.x;
    if (o < 49152) {                               // 3*128*128 weights
        int m = o >> 14, rem = o & 16383;
        int nn = rem >> 7, kk = rem & 127;
        const float* W = (m == 0) ? Wq : (m == 1) ? Wp : Wv;
        Wt[o] = __float2half(W[kk * 128 + nn]);
    } else {
        int i = o - 49152;
        if (i < N) deg[i] = 0;
    }
}

// ---------------- D1: mixed dispatch -- gemm blocks + count blocks ----------
__global__ __launch_bounds__(256) void gemm_scatter_kernel(
    const float* __restrict__ h, const __half* __restrict__ Wt,
    unsigned* __restrict__ KV, __half* __restrict__ Q, int n,
    const int* __restrict__ dst, int* __restrict__ deg,
    int E, int gemm_blocks)
{
    __shared__ __align__(16) char smem[34816];
    const int t = threadIdx.x;

    if ((int)blockIdx.x < gemm_blocks) {
        // ------------------ GEMM branch (MFMA 16x16x32 f16) ------------------
        _Float16* ws = (_Float16*)smem;            // 128 x 136 halves
        const int wid = t >> 6, lane = t & 63;
        const int node0 = blockIdx.x * HNODE;
        const int mrow = lane & 15, quad = lane >> 4;

        const int row = node0 + wid * 16 + mrow;
        const bool rowvalid = (row < n);
        const int rowc = rowvalid ? row : (n - 1);

        f16x8 hfr[4];
        #pragma unroll
        for (int s = 0; s < 4; s++) {
            const float4* hp = (const float4*)(h + (size_t)rowc * 128 + quad * 8 + 32 * s);
            float4 f0 = hp[0], f1 = hp[1];
            f16x8 a;
            a[0] = (_Float16)f0.x; a[1] = (_Float16)f0.y;
            a[2] = (_Float16)f0.z; a[3] = (_Float16)f0.w;
            a[4] = (_Float16)f1.x; a[5] = (_Float16)f1.y;
            a[6] = (_Float16)f1.z; a[7] = (_Float16)f1.w;
            hfr[s] = a;
        }

        f32x4 acc[3][8];
        #pragma unroll
        for (int m = 0; m < 3; m++)
            #pragma unroll
            for (int ct = 0; ct < 8; ct++) acc[m][ct] = (f32x4){0.f, 0.f, 0.f, 0.f};

        #pragma unroll
        for (int m = 0; m < 3; m++) {
            __syncthreads();
            {
                const uint4* wg = (const uint4*)(Wt + (size_t)m * 16384);
                #pragma unroll
                for (int i = 0; i < 8; i++) {
                    int idx = t * 8 + i;            // 0..2047
                    int r = idx >> 4, seg = idx & 15;
                    *(uint4*)(ws + r * 136 + seg * 8) = wg[idx];
                }
            }
            __syncthreads();
            #pragma unroll
            for (int s = 0; s < 4; s++) {
                #pragma unroll
                for (int ct = 0; ct < 8; ct++) {
                    f16x8 a = *(const f16x8*)(ws + (ct * 16 + mrow) * 136 + quad * 8 + 32 * s);
                    acc[m][ct] = __builtin_amdgcn_mfma_f32_16x16x32_f16(a, hfr[s], acc[m][ct], 0, 0, 0);
                }
            }
        }

        if (rowvalid) {
            // head-major epilogue: for MFMA tile ct, head = ct, quarter = quad
            #pragma unroll
            for (int ct = 0; ct < 8; ct++) {
                uint4 ov;
                ov.x = pack2(acc[0][ct][0], acc[0][ct][1]);   // K pair
                ov.y = pack2(acc[0][ct][2], acc[0][ct][3]);
                ov.z = pack2(acc[2][ct][0], acc[2][ct][1]);   // V pair
                ov.w = pack2(acc[2][ct][2], acc[2][ct][3]);
                *(uint4*)(KV + (((size_t)ct * n + row) << 4) + 4 * quad) = ov;
                uint2 qv;
                qv.x = pack2(acc[1][ct][0], acc[1][ct][1]);
                qv.y = pack2(acc[1][ct][2], acc[1][ct][3]);
                *(uint2*)(Q + (((size_t)ct * n + row) << 4) + 4 * quad) = qv;
            }
        }
    } else {
        // ------------------ count branch: deg[dst]++ (no LDS, no barriers) ---
        int blk = blockIdx.x - gemm_blocks;
        int base = blk * EPB + t * 4;
        #pragma unroll
        for (int r = 0; r < 4; r++) {
            int i = base + r * 1024;
            int4 dv;
            if (i + 3 < E) {
                dv = *(const int4*)(dst + i);
            } else {
                dv.x = (i     < E) ? dst[i]     : -1;
                dv.y = (i + 1 < E) ? dst[i + 1] : -1;
                dv.z = (i + 2 < E) ? dst[i + 2] : -1;
                dv.w = (i + 3 < E) ? dst[i + 3] : -1;
            }
            if (dv.x >= 0) atomicAdd(&deg[dv.x], 1);
            if (dv.y >= 0) atomicAdd(&deg[dv.y], 1);
            if (dv.z >= 0) atomicAdd(&deg[dv.z], 1);
            if (dv.w >= 0) atomicAdd(&deg[dv.w], 1);
        }
    }
}

// ---------------- D2: per-bucket offsets + cursor + degree order ------------
// one block per 128-node bucket; fixed segment base seg0 = b*BKT_CAP keeps
// csr segmenting identical to the old fine_scatter (no cross-bucket scan).
__global__ __launch_bounds__(128) void bucket_offsets_kernel(
    const int* __restrict__ deg, int2* __restrict__ offs,
    int* __restrict__ cursor, int* __restrict__ nodeord, int N)
{
    __shared__ int sdeg[128];
    __shared__ int ts[128];
    int b = blockIdx.x, t = threadIdx.x;
    int node = (b << 7) + t;
    int d = (node < N) ? deg[node] : 0;
    sdeg[t] = d;
    ts[t] = d;
    __syncthreads();
    for (int off = 1; off < 128; off <<= 1) {
        int x = ts[t];
        int y = (t >= off) ? ts[t - off] : 0;
        __syncthreads();
        ts[t] = x + y;
        __syncthreads();
    }
    int pfx = ts[t] - d;
    int seg0 = b * BKT_CAP;
    if (node < N) {
        offs[node] = make_int2(seg0 + pfx, seg0 + pfx + d);
        cursor[node] = seg0 + pfx;
    }
    // stable descending-degree rank -> nodeord (same semantics as before)
    int r = 0;
    #pragma unroll 8
    for (int j = 0; j < 128; j++) {
        int dj = sdeg[j];
        r += (int)((dj > d) || (dj == d && j < t));
    }
    nodeord[(b << 7) + r] = t;
}

// ---------------- D3: edge placement csr[atomic cursor] = src ---------------
__global__ __launch_bounds__(256) void place_kernel(
    const int* __restrict__ src, const int* __restrict__ dst,
    int* __restrict__ cursor, unsigned short* __restrict__ csr, int E)
{
    const int t = threadIdx.x;
    int base = blockIdx.x * EPB + t * 4;
    #pragma unroll
    for (int r = 0; r < 4; r++) {
        int i = base + r * 1024;
        int4 sv, dv;
        if (i + 3 < E) {
            sv = *(const int4*)(src + i);
            dv = *(const int4*)(dst + i);
        } else {
            sv.x = (i     < E) ? src[i]     : 0;
            sv.y = (i + 1 < E) ? src[i + 1] : 0;
            sv.z = (i + 2 < E) ? src[i + 2] : 0;
            sv.w = (i + 3 < E) ? src[i + 3] : 0;
            dv.x = (i     < E) ? dst[i]     : -1;
            dv.y = (i + 1 < E) ? dst[i + 1] : -1;
            dv.z = (i + 2 < E) ? dst[i + 2] : -1;
            dv.w = (i + 3 < E) ? dst[i + 3] : -1;
        }
        int pos, lim;
        if (dv.x >= 0) {
            pos = atomicAdd(&cursor[dv.x], 1);
            lim = ((dv.x >> BKT_SHIFT) + 1) * BKT_CAP;
            if (pos < lim) csr[pos] = (unsigned short)sv.x;
        }
        if (dv.y >= 0) {
            pos = atomicAdd(&cursor[dv.y], 1);
            lim = ((dv.y >> BKT_SHIFT) + 1) * BKT_CAP;
            if (pos < lim) csr[pos] = (unsigned short)sv.y;
        }
        if (dv.z >= 0) {
            pos = atomicAdd(&cursor[dv.z], 1);
            lim = ((dv.z >> BKT_SHIFT) + 1) * BKT_CAP;
            if (pos < lim) csr[pos] = (unsigned short)sv.z;
        }
        if (dv.w >= 0) {
            pos = atomicAdd(&cursor[dv.w], 1);
            lim = ((dv.w >> BKT_SHIFT) + 1) * BKT_CAP;
            if (pos < lim) csr[pos] = (unsigned short)sv.w;
        }
    }
}

// ---------------- D4: aggregation, head-per-XCD, quad-per-edge, 4-deep ------
// grid = nbkt*2*8; head = blockIdx&7 (XCD pin). Block = 64 degree-similar
// nodes of one bucket (rank chunks interleaved across the two sub-blocks).
// Wave = 16 quads; quad = one node, lane p = feature quarter p.
#define AGG_COMPUTE(A, J)                                                      \
    {                                                                          \
        float s = fdot2(A.x, qq.x, fdot2(A.y, qq.y, 0.f));                     \
        s = qadd_xor1(s);                                                      \
        s = qadd_xor2(s);                                                      \
        float xx = clamp5(s * 0.25f);                                          \
        float sc = (e + (J) < cnt) ? __expf(xx) : 0.f;                         \
        accz += sc;                                                            \
        float2 v0 = h2f(A.z), v1 = h2f(A.w);                                   \
        av0 += sc * v0.x; av1 += sc * v0.y;                                    \
        av2 += sc * v1.x; av3 += sc * v1.y;                                    \
    }

__global__ __launch_bounds__(256) void aggregate_kernel(
    const unsigned* __restrict__ KVh,          // [H][N] 64B rows
    const uint2* __restrict__ Qr,              // [H][N] 4x uint2
    const int2* __restrict__ offs, const unsigned short* __restrict__ csr,
    const int* __restrict__ nodeord,
    float* __restrict__ out, int n)
{
    const int t = threadIdx.x;
    const int head = blockIdx.x & 7;
    const int rest = blockIdx.x >> 3;
    const int bkt = rest >> 1, sub = rest & 1;
    const int lane = t & 63;
    const int g = lane >> 2;          // quad (node slot) 0..15
    const int p = lane & 3;           // feature quarter
    const int chunk = ((t >> 6) << 1) | sub;   // interleave rank chunks

    const int spos = (bkt << 7) + (chunk << 4) + g;
    const int local = nodeord[spos];
    const int node = (bkt << 7) + local;
    const bool nvalid = (node < n);
    const int nodec = nvalid ? node : 0;

    int beg = 0, cnt = 0;
    if (nvalid) {
        int2 be = offs[node];
        beg = be.x; cnt = be.y - be.x;
    }

    const size_t hn = (size_t)head * n;
    const uint2 qq = Qr[(hn + nodec) * 4 + p];
    const char* kvb = (const char*)KVh + hn * 64;     // wave-uniform base
    const unsigned ppo = (unsigned)p << 4;            // per-lane 16B quarter

    float accz = 0.f;
    float av0 = 0.f, av1 = 0.f, av2 = 0.f, av3 = 0.f;

    const int cl = (cnt > 0) ? (cnt - 1) : 0;

    // prime: csr vector + 4 gathers for group 0, csr vector for group 1
    int np = (p < cl) ? p : cl;
    int idxA = (int)csr[beg + np];
    uint4 a0, a1, a2, a3;
    {
        unsigned j;
        j = (unsigned)QBCAST(idxA, 0); a0 = *(const uint4*)(kvb + ((j << 6) | ppo));
        j = (unsigned)QBCAST(idxA, 1); a1 = *(const uint4*)(kvb + ((j << 6) | ppo));
        j = (unsigned)QBCAST(idxA, 2); a2 = *(const uint4*)(kvb + ((j << 6) | ppo));
        j = (unsigned)QBCAST(idxA, 3); a3 = *(const uint4*)(kvb + ((j << 6) | ppo));
    }
    np = 4 + p; np = (np < cl) ? np : cl;
    int idxB = (int)csr[beg + np];

    for (int e = 0; e < cnt; e += 4) {
        // issue group g+1 gathers (indices from csr vector loaded last iter)
        unsigned j;
        uint4 b0, b1, b2, b3;
        j = (unsigned)QBCAST(idxB, 0); b0 = *(const uint4*)(kvb + ((j << 6) | ppo));
        j = (unsigned)QBCAST(idxB, 1); b1 = *(const uint4*)(kvb + ((j << 6) | ppo));
        j = (unsigned)QBCAST(idxB, 2); b2 = *(const uint4*)(kvb + ((j << 6) | ppo));
        j = (unsigned)QBCAST(idxB, 3); b3 = *(const uint4*)(kvb + ((j << 6) | ppo));
        // csr vector for group g+2
        np = e + 8 + p; np = (np < cl) ? np : cl;
        idxB = (int)csr[beg + np];

        // compute group g (loads issued last iteration: full-iter latency)
        AGG_COMPUTE(a0, 0)
        AGG_COMPUTE(a1, 1)
        AGG_COMPUTE(a2, 2)
        AGG_COMPUTE(a3, 3)

        a0 = b0; a1 = b1; a2 = b2; a3 = b3;
    }

    if (nvalid) {
        float z = accz;
        if (z == 0.f) z = 0.001f;
        float inv = 1.0f / z;
        *(float4*)(out + (size_t)node * 128 + head * 16 + p * 4) =
            make_float4(av0 * inv, av1 * inv, av2 * inv, av3 * inv);
    }
}

// ---------------------------------------------------------------------------

extern "C" void kernel_launch(void* const* d_in, const int* in_sizes, int n_in,
                              void* d_out, int out_size, void* d_ws, size_t ws_size,
                              hipStream_t stream)
{
    const float* h   = (const float*)d_in[0];
    const int*   src = (const int*)d_in[1];
    const int*   dst = (const int*)d_in[2];
    const float* p   = (const float*)d_in[3];
    const float* q   = (const float*)d_in[4];
    const float* wv  = (const float*)d_in[5];
    float* out = (float*)d_out;

    const int N = in_sizes[0] / 128;
    const int E = in_sizes[1];
    const int nbkt = (N + 127) >> BKT_SHIFT;     // 391 for N=50000
    const int nblk_e = (E + EPB - 1) / EPB;      // 391 for E=1.6M
    const int gemm_blocks = (N + HNODE - 1) / HNODE;   // 782

    unsigned* KV = (unsigned*)d_ws;                            // H*N*16 u32 (25.6MB)
    __half* Qh   = (__half*)(KV + (size_t)N * 128);            // H*N*16 half (12.8MB)
    unsigned short* csr16 = (unsigned short*)(Qh + (size_t)N * 128); // nbkt*BKT_CAP u16 (4MB)
    int2* offs   = (int2*)(csr16 + (size_t)nbkt * BKT_CAP);    // N
    int* nodeord = (int*)(offs + N);                           // nbkt*128
    int* deg     = nodeord + (size_t)nbkt * 128;               // N
    int* cursor  = deg + N;                                    // N
    __half* Wt   = (__half*)(cursor + N);                      // 3*128*128 halves

    const int d0_blocks = 192 + (N + 255) / 256;

    wt_convert_kernel<<<d0_blocks, 256, 0, stream>>>(q, p, wv, Wt, deg, N);

    gemm_scatter_kernel<<<gemm_blocks + nblk_e, 256, 0, stream>>>(
        h, Wt, KV, Qh, N, dst, deg, E, gemm_blocks);

    bucket_offsets_kernel<<<nbkt, 128, 0, stream>>>(deg, offs, cursor, nodeord, N);

    place_kernel<<<nblk_e, 256, 0, stream>>>(src, dst, cursor, csr16, E);

    aggregate_kernel<<<nbkt * 16, 256, 0, stream>>>(
        KV, (const uint2*)Qh, offs, csr16, nodeord, (float*)out, N);
}

// Round 6
// 279.931 us; speedup vs baseline: 1.2876x; 1.2876x over previous
//
#include <hip/hip_runtime.h>
#include <hip/hip_fp16.h>

// ---------------------------------------------------------------------------
// IN=128, H=8, R=16, D=16 -> H*R = H*D = 128
// K = h @ q, Q = h @ p, V = h @ Wv   (K uses weight "q", Q uses weight "p")
// score = exp(clip((K[src]*Q[dst]).sum(r)/4, -5, 5))
// out = seg_sum(score*V[src], dst) / max(seg_sum(score,dst), eps-fixup)
//
// R13: head-per-XCD aggregation (head = blockIdx&7): per-head KV slice is
//      3.2MB -> fits one XCD's 4MiB L2. FETCH 350MB -> 55MB (verified).
// R15: quad-per-edge (1 line-touch/edge-head, DPP quad ops): 150 -> 90us.
// R16: deeper pipeline: no change -> aggregate sits at a scattered-64B
//      service/TLP floor (~89us). Leave the gather loop alone.
// R17 (FAILED, reverted): global-atomic counting sort. Device-scope atomics
//      to scattered addresses ~60ns serial-equivalent (dispatch 96% idle,
//      +49MB atomic write thrash). LDS bucket sort is strictly better.
// R18: fuse fine_scatter INTO aggregate. Each (bucket,head) block builds the
//      bucket CSR in LDS from ebuf/cnts (8x replicated, L3-resident reads),
//      then aggregates its 128 nodes (8 waves x 16 quads) with edge indices
//      read from LDS. Deletes the occupancy-starved fine_scatter dispatch,
//      its gap, and the csr/offs global round-trip; sort latency hides in
//      aggregate's idle issue slots (both pipes <40%).
// ---------------------------------------------------------------------------

#define HNODE 64        // nodes per GEMM block
#define EPB   4096      // edges per scatter block (short chains, more blocks)
#define BKT_SHIFT 7     // 128 nodes per bucket
#define BKT_CAP 5120    // bucket mean 4092 + 16 sigma
#define CHUNK 40        // per-(bucket,block) slots; Poisson(10.5)+9sigma

typedef _Float16 f16x8 __attribute__((ext_vector_type(8)));
typedef float    f32x4 __attribute__((ext_vector_type(4)));
typedef _Float16 hv2   __attribute__((ext_vector_type(2)));

__device__ __forceinline__ float fdot2(unsigned a, unsigned b, float c) {
#if __has_builtin(__builtin_amdgcn_fdot2)
    return __builtin_amdgcn_fdot2(__builtin_bit_cast(hv2, a),
                                  __builtin_bit_cast(hv2, b), c, false);
#else
    __half2 ah = *(__half2*)&a, bh = *(__half2*)&b;
    float2 af = __half22float2(ah), bf = __half22float2(bh);
    return c + af.x * bf.x + af.y * bf.y;
#endif
}

__device__ __forceinline__ float2 h2f(unsigned u) {
    __half2 hh = *(__half2*)&u;
    return __half22float2(hh);
}

__device__ __forceinline__ unsigned pack2(float a, float b) {
    __half2 hh = __floats2half2_rn(a, b);
    return *(unsigned*)&hh;
}

__device__ __forceinline__ float clamp5(float x) {
#if __has_builtin(__builtin_amdgcn_fmed3f)
    return __builtin_amdgcn_fmed3f(x, -5.f, 5.f);   // v_med3_f32 = clamp idiom
#else
    return fminf(fmaxf(x, -5.f), 5.f);
#endif
}

// ---- quad-scope cross-lane via DPP (VALU pipe, no LDS traffic) -------------
#if __has_builtin(__builtin_amdgcn_mov_dpp)
#define QBCAST(v, J) __builtin_amdgcn_mov_dpp((v), (J) * 0x55, 0xF, 0xF, true)
__device__ __forceinline__ float qadd_xor1(float x) {
    int y = __builtin_amdgcn_mov_dpp(__float_as_int(x), 0xB1, 0xF, 0xF, true);
    return x + __int_as_float(y);
}
__device__ __forceinline__ float qadd_xor2(float x) {
    int y = __builtin_amdgcn_mov_dpp(__float_as_int(x), 0x4E, 0xF, 0xF, true);
    return x + __int_as_float(y);
}
#else
#define QBCAST(v, J) __shfl((v), ((threadIdx.x & 63) & ~3) + (J), 64)
__device__ __forceinline__ float qadd_xor1(float x) { return x + __shfl_xor(x, 1); }
__device__ __forceinline__ float qadd_xor2(float x) { return x + __shfl_xor(x, 2); }
#endif

// ---------------- D0: weight transpose+convert W[k][n] fp32 -> Wt[m][n][k] --
__global__ __launch_bounds__(256) void wt_convert_kernel(
    const float* __restrict__ Wq, const float* __restrict__ Wp,
    const float* __restrict__ Wv, __half* __restrict__ Wt)
{
    int o = blockIdx.x * 256 + threadIdx.x;      // 3*128*128 total
    int m = o >> 14, rem = o & 16383;
    int nn = rem >> 7, kk = rem & 127;
    const float* W = (m == 0) ? Wq : (m == 1) ? Wp : Wv;
    Wt[o] = __float2half(W[kk * 128 + nn]);
}

// ---------------- D1: mixed dispatch -- gemm blocks + scatter blocks --------
__global__ __launch_bounds__(256) void gemm_scatter_kernel(
    const float* __restrict__ h, const __half* __restrict__ Wt,
    unsigned* __restrict__ KV, __half* __restrict__ Q, int n,
    const int* __restrict__ src, const int* __restrict__ dst,
    unsigned* __restrict__ ebuf, int* __restrict__ cnts,
    int E, int nbkt, int nblk_e, int gemm_blocks)
{
    __shared__ __align__(16) char smem[39936];
    const int t = threadIdx.x;

    if ((int)blockIdx.x < gemm_blocks) {
        // ------------------ GEMM branch (MFMA 16x16x32 f16) ------------------
        _Float16* ws = (_Float16*)smem;            // 128 x 136 halves
        const int wid = t >> 6, lane = t & 63;
        const int node0 = blockIdx.x * HNODE;
        const int mrow = lane & 15, quad = lane >> 4;

        const int row = node0 + wid * 16 + mrow;
        const bool rowvalid = (row < n);
        const int rowc = rowvalid ? row : (n - 1);

        f16x8 hfr[4];
        #pragma unroll
        for (int s = 0; s < 4; s++) {
            const float4* hp = (const float4*)(h + (size_t)rowc * 128 + quad * 8 + 32 * s);
            float4 f0 = hp[0], f1 = hp[1];
            f16x8 a;
            a[0] = (_Float16)f0.x; a[1] = (_Float16)f0.y;
            a[2] = (_Float16)f0.z; a[3] = (_Float16)f0.w;
            a[4] = (_Float16)f1.x; a[5] = (_Float16)f1.y;
            a[6] = (_Float16)f1.z; a[7] = (_Float16)f1.w;
            hfr[s] = a;
        }

        f32x4 acc[3][8];
        #pragma unroll
        for (int m = 0; m < 3; m++)
            #pragma unroll
            for (int ct = 0; ct < 8; ct++) acc[m][ct] = (f32x4){0.f, 0.f, 0.f, 0.f};

        #pragma unroll
        for (int m = 0; m < 3; m++) {
            __syncthreads();
            {
                const uint4* wg = (const uint4*)(Wt + (size_t)m * 16384);
                #pragma unroll
                for (int i = 0; i < 8; i++) {
                    int idx = t * 8 + i;            // 0..2047
                    int r = idx >> 4, seg = idx & 15;
                    *(uint4*)(ws + r * 136 + seg * 8) = wg[idx];
                }
            }
            __syncthreads();
            #pragma unroll
            for (int s = 0; s < 4; s++) {
                #pragma unroll
                for (int ct = 0; ct < 8; ct++) {
                    f16x8 a = *(const f16x8*)(ws + (ct * 16 + mrow) * 136 + quad * 8 + 32 * s);
                    acc[m][ct] = __builtin_amdgcn_mfma_f32_16x16x32_f16(a, hfr[s], acc[m][ct], 0, 0, 0);
                }
            }
        }

        if (rowvalid) {
            // head-major epilogue: for MFMA tile ct, head = ct, quarter = quad
            #pragma unroll
            for (int ct = 0; ct < 8; ct++) {
                uint4 ov;
                ov.x = pack2(acc[0][ct][0], acc[0][ct][1]);   // K pair
                ov.y = pack2(acc[0][ct][2], acc[0][ct][3]);
                ov.z = pack2(acc[2][ct][0], acc[2][ct][1]);   // V pair
                ov.w = pack2(acc[2][ct][2], acc[2][ct][3]);
                *(uint4*)(KV + (((size_t)ct * n + row) << 4) + 4 * quad) = ov;
                uint2 qv;
                qv.x = pack2(acc[1][ct][0], acc[1][ct][1]);
                qv.y = pack2(acc[1][ct][2], acc[1][ct][3]);
                *(uint2*)(Q + (((size_t)ct * n + row) << 4) + 4 * quad) = qv;
            }
        }
    } else {
        // ------------------ scatter branch (bucket sort in LDS) --------------
        unsigned long long* sorted = (unsigned long long*)smem;   // 4096 (32KB)
        int* cnt  = (int*)(smem + 32768);                         // 512
        int* lofs = (int*)(smem + 34816);                         // 512
        int* ts   = (int*)(smem + 36864);                         // 256
        int* tot_sh = (int*)(smem + 37888);

        int blk = blockIdx.x - gemm_blocks;
        for (int i = t; i < 512; i += 256) cnt[i] = 0;
        __syncthreads();

        int4 sv[4], dv[4], rk[4];
        int base = blk * EPB + t * 4;
        #pragma unroll
        for (int r = 0; r < 4; r++) {
            int i = base + r * 1024;
            if (i + 3 < E) {
                sv[r] = *(const int4*)(src + i);
                dv[r] = *(const int4*)(dst + i);
            } else {
                int tsrc[4], tdst[4];
                for (int k = 0; k < 4; k++) {
                    int j = i + k;
                    tsrc[k] = (j < E) ? src[j] : 0;
                    tdst[k] = (j < E) ? dst[j] : -1;
                }
                sv[r] = make_int4(tsrc[0], tsrc[1], tsrc[2], tsrc[3]);
                dv[r] = make_int4(tdst[0], tdst[1], tdst[2], tdst[3]);
            }
            rk[r].x = (dv[r].x >= 0) ? atomicAdd(&cnt[dv[r].x >> BKT_SHIFT], 1) : 0;
            rk[r].y = (dv[r].y >= 0) ? atomicAdd(&cnt[dv[r].y >> BKT_SHIFT], 1) : 0;
            rk[r].z = (dv[r].z >= 0) ? atomicAdd(&cnt[dv[r].z >> BKT_SHIFT], 1) : 0;
            rk[r].w = (dv[r].w >= 0) ? atomicAdd(&cnt[dv[r].w >> BKT_SHIFT], 1) : 0;
        }
        __syncthreads();

        for (int i = t; i < nbkt; i += 256)
            cnts[blk * 512 + i] = cnt[i];

        // exclusive scan over 512 bucket counts (thread t owns 2t, 2t+1)
        int c0 = cnt[2 * t], c1 = cnt[2 * t + 1];
        int ps = c0 + c1;
        ts[t] = ps; __syncthreads();
        for (int off = 1; off < 256; off <<= 1) {
            int x = ts[t];
            int y = (t >= off) ? ts[t - off] : 0;
            __syncthreads();
            ts[t] = x + y;
            __syncthreads();
        }
        int pbase = ts[t] - ps;
        lofs[2 * t] = pbase;
        lofs[2 * t + 1] = pbase + c0;
        if (t == 255) *tot_sh = ts[255];
        __syncthreads();

        #pragma unroll
        for (int r = 0; r < 4; r++) {
            int s, d;
            d = dv[r].x; if (d >= 0) { s = sv[r].x; sorted[lofs[d >> BKT_SHIFT] + rk[r].x] = ((unsigned long long)d << 18) | (unsigned)s; }
            d = dv[r].y; if (d >= 0) { s = sv[r].y; sorted[lofs[d >> BKT_SHIFT] + rk[r].y] = ((unsigned long long)d << 18) | (unsigned)s; }
            d = dv[r].z; if (d >= 0) { s = sv[r].z; sorted[lofs[d >> BKT_SHIFT] + rk[r].z] = ((unsigned long long)d << 18) | (unsigned)s; }
            d = dv[r].w; if (d >= 0) { s = sv[r].w; sorted[lofs[d >> BKT_SHIFT] + rk[r].w] = ((unsigned long long)d << 18) | (unsigned)s; }
        }
        __syncthreads();

        int tot = *tot_sh;
        #pragma unroll
        for (int j = 0; j < 16; j++) {
            int i = j * 256 + t;
            if (i < tot) {
                unsigned long long e = sorted[i];
                int d = (int)(e >> 18);
                int b = d >> BKT_SHIFT;
                int k = i - lofs[b];
                if (k < CHUNK)
                    ebuf[((size_t)b * nblk_e + blk) * CHUNK + k] =
                        ((unsigned)(d & 127) << 18) | (unsigned)(e & 0x3FFFFu);
            }
        }
    }
}

// ---------------- D2: FUSED per-bucket fine sort (LDS) + aggregation --------
// grid = nbkt*8, 512 threads; head = blockIdx&7 (XCD pin), bkt = blockIdx>>3.
// Phase 1 (replicated per head): build the bucket CSR entirely in LDS from
// ebuf/cnts -- 512-scan of chunk counts, gather, LDS-atomic per-node ranks,
// 128-scan, stable degree order lord[].
// Phase 2: 8 waves x 16 quads = 128 nodes (wave w takes ranks w*16..w*16+15,
// degree-similar). Quad = one node, lane p = feature quarter. Per edge: ONE
// 64B KV row gather, 2 fdot2 + DPP quad reduce, exp, 4 V-FMAs; edge indices
// from LDS lcsr (ds_read_u16), 4-edge double-buffered groups.
#define AGG_COMPUTE(A, J)                                                      \
    {                                                                          \
        float s = fdot2(A.x, qq.x, fdot2(A.y, qq.y, 0.f));                     \
        s = qadd_xor1(s);                                                      \
        s = qadd_xor2(s);                                                      \
        float xx = clamp5(s * 0.25f);                                          \
        float sc = (e + (J) < cnt) ? __expf(xx) : 0.f;                         \
        accz += sc;                                                            \
        float2 v0 = h2f(A.z), v1 = h2f(A.w);                                   \
        av0 += sc * v0.x; av1 += sc * v0.y;                                    \
        av2 += sc * v1.x; av3 += sc * v1.y;                                    \
    }

__global__ __launch_bounds__(512) void aggregate_kernel(
    const unsigned* __restrict__ KVh,          // [H][N] 64B rows
    const uint2* __restrict__ Qr,              // [H][N] 4x uint2
    const unsigned* __restrict__ ebuf, const int* __restrict__ cnts,
    float* __restrict__ out, int n, int nblk_e)
{
    __shared__ int cval[512];
    __shared__ int cofs[512];
    __shared__ int ts[512];
    __shared__ int ldeg[128];
    __shared__ int lstart[128];
    __shared__ unsigned char lord[128];
    __shared__ int tot_sh;
    __shared__ unsigned sedge[BKT_CAP];
    __shared__ unsigned short srank[BKT_CAP];
    __shared__ unsigned short lcsr[BKT_CAP];

    const int t = threadIdx.x;
    const int head = blockIdx.x & 7;
    const int b = blockIdx.x >> 3;             // bucket

    // ---------------- phase 1: bucket CSR in LDS ----------------
    int c = (t < nblk_e) ? cnts[t * 512 + b] : 0;
    if (c > CHUNK) c = CHUNK;
    cval[t] = c;
    ts[t] = c;
    if (t < 128) ldeg[t] = 0;
    __syncthreads();
    for (int off = 1; off < 512; off <<= 1) {
        int x = ts[t];
        int y = (t >= off) ? ts[t - off] : 0;
        __syncthreads();
        ts[t] = x + y;
        __syncthreads();
    }
    cofs[t] = ts[t] - cval[t];
    if (t == 511) tot_sh = (ts[511] <= BKT_CAP) ? ts[511] : BKT_CAP;
    __syncthreads();

    for (int idx = t; idx < nblk_e * CHUNK; idx += 512) {
        int cc = idx / CHUNK, k = idx - cc * CHUNK;
        if (k < cval[cc]) {
            int pos = cofs[cc] + k;
            if (pos < BKT_CAP)
                sedge[pos] = ebuf[((size_t)b * nblk_e + cc) * CHUNK + k];
        }
    }
    __syncthreads();

    const int tot = tot_sh;
    for (int i = t; i < tot; i += 512)
        srank[i] = (unsigned short)atomicAdd(&ldeg[sedge[i] >> 18], 1);
    __syncthreads();

    int mydeg = (t < 128) ? ldeg[t] : 0;
    if (t < 128) ts[t] = mydeg;
    __syncthreads();
    for (int off = 1; off < 128; off <<= 1) {
        int x = (t < 128) ? ts[t] : 0;
        int y = (t >= off && t < 128) ? ts[t - off] : 0;
        __syncthreads();
        if (t < 128) ts[t] = x + y;
        __syncthreads();
    }
    if (t < 128) {
        lstart[t] = ts[t] - mydeg;
        // stable descending-degree rank -> lord (degree-similar quads/wave)
        int r = 0;
        for (int j = 0; j < 128; j++) {
            int dj = ldeg[j];
            r += (int)((dj > mydeg) || (dj == mydeg && j < t));
        }
        lord[r] = (unsigned char)t;
    }
    __syncthreads();

    for (int i = t; i < tot; i += 512) {
        unsigned v = sedge[i];
        lcsr[lstart[v >> 18] + srank[i]] = (unsigned short)(v & 0x3FFFFu);
    }
    __syncthreads();

    // ---------------- phase 2: aggregate 128 nodes --------------
    const int lane = t & 63;
    const int w = t >> 6;                 // wave 0..7
    const int g = lane >> 2;              // quad (node slot) 0..15
    const int p = lane & 3;               // feature quarter

    const int local = (int)lord[w * 16 + g];
    const int node = (b << 7) + local;
    const bool nvalid = (node < n);
    const int nodec = nvalid ? node : 0;

    const int lbeg = lstart[local];
    const int cnt = ldeg[local];

    const size_t hn = (size_t)head * n;
    const uint2 qq = Qr[(hn + nodec) * 4 + p];
    const char* kvb = (const char*)KVh + hn * 64;     // wave-uniform base
    const unsigned ppo = (unsigned)p << 4;            // per-lane 16B quarter

    float accz = 0.f;
    float av0 = 0.f, av1 = 0.f, av2 = 0.f, av3 = 0.f;

    const int cl = (cnt > 0) ? (cnt - 1) : 0;

    // prime: lcsr vector + 4 gathers for group 0, lcsr vector for group 1
    int np = (p < cl) ? p : cl;
    int idxA = (int)lcsr[lbeg + np];
    uint4 a0, a1, a2, a3;
    {
        unsigned j;
        j = (unsigned)QBCAST(idxA, 0); a0 = *(const uint4*)(kvb + ((j << 6) | ppo));
        j = (unsigned)QBCAST(idxA, 1); a1 = *(const uint4*)(kvb + ((j << 6) | ppo));
        j = (unsigned)QBCAST(idxA, 2); a2 = *(const uint4*)(kvb + ((j << 6) | ppo));
        j = (unsigned)QBCAST(idxA, 3); a3 = *(const uint4*)(kvb + ((j << 6) | ppo));
    }
    np = 4 + p; np = (np < cl) ? np : cl;
    int idxB = (int)lcsr[lbeg + np];

    for (int e = 0; e < cnt; e += 4) {
        // issue group g+1 gathers (indices from lcsr vector loaded last iter)
        unsigned j;
        uint4 b0, b1, b2, b3;
        j = (unsigned)QBCAST(idxB, 0); b0 = *(const uint4*)(kvb + ((j << 6) | ppo));
        j = (unsigned)QBCAST(idxB, 1); b1 = *(const uint4*)(kvb + ((j << 6) | ppo));
        j = (unsigned)QBCAST(idxB, 2); b2 = *(const uint4*)(kvb + ((j << 6) | ppo));
        j = (unsigned)QBCAST(idxB, 3); b3 = *(const uint4*)(kvb + ((j << 6) | ppo));
        // lcsr vector for group g+2
        np = e + 8 + p; np = (np < cl) ? np : cl;
        idxB = (int)lcsr[lbeg + np];

        // compute group g
        AGG_COMPUTE(a0, 0)
        AGG_COMPUTE(a1, 1)
        AGG_COMPUTE(a2, 2)
        AGG_COMPUTE(a3, 3)

        a0 = b0; a1 = b1; a2 = b2; a3 = b3;
    }

    if (nvalid) {
        float z = accz;
        if (z == 0.f) z = 0.001f;
        float inv = 1.0f / z;
        *(float4*)(out + (size_t)node * 128 + head * 16 + p * 4) =
            make_float4(av0 * inv, av1 * inv, av2 * inv, av3 * inv);
    }
}

// ---------------------------------------------------------------------------

extern "C" void kernel_launch(void* const* d_in, const int* in_sizes, int n_in,
                              void* d_out, int out_size, void* d_ws, size_t ws_size,
                              hipStream_t stream)
{
    const float* h   = (const float*)d_in[0];
    const int*   src = (const int*)d_in[1];
    const int*   dst = (const int*)d_in[2];
    const float* p   = (const float*)d_in[3];
    const float* q   = (const float*)d_in[4];
    const float* wv  = (const float*)d_in[5];
    float* out = (float*)d_out;

    const int N = in_sizes[0] / 128;
    const int E = in_sizes[1];
    const int nbkt = (N + 127) >> BKT_SHIFT;     // 391 for N=50000 (<=512)
    const int nblk_e = (E + EPB - 1) / EPB;      // 391 for E=1.6M (<=512)
    const int gemm_blocks = (N + HNODE - 1) / HNODE;   // 782

    unsigned* KV = (unsigned*)d_ws;                            // H*N*16 u32 (25.6MB)
    __half* Qh   = (__half*)(KV + (size_t)N * 128);            // H*N*16 half (12.8MB)
    unsigned* ebuf = (unsigned*)(Qh + (size_t)N * 128);        // nbkt*nblk_e*CHUNK u32 (~24.5MB)
    int* cnts    = (int*)(ebuf + (size_t)nbkt * nblk_e * CHUNK); // nblk_e*512
    __half* Wt   = (__half*)(cnts + (size_t)nblk_e * 512);     // 3*128*128 halves

    wt_convert_kernel<<<192, 256, 0, stream>>>(q, p, wv, Wt);

    gemm_scatter_kernel<<<gemm_blocks + nblk_e, 256, 0, stream>>>(
        h, Wt, KV, Qh, N, src, dst, ebuf, cnts, E, nbkt, nblk_e, gemm_blocks);

    aggregate_kernel<<<nbkt * 8, 512, 0, stream>>>(
        KV, (const uint2*)Qh, ebuf, cnts, (float*)out, N, nblk_e);
}